// Round 1
// baseline (684.729 us; speedup 1.0000x reference)
//
#include <hip/hip_runtime.h>

#define NBATCH 8
#define NTOK   12
#define NN     207
#define DD     64
#define DHID   256
#define LL     2484      // NTOK*NN
#define RR     6         // rows per block in k_attn (divides 2484)
#define NJ     10        // ceil(2484/256)
#define LNEPS  1e-5f

// ---------------- Kernel 1: LayerNorm + Q/K projections ----------------
__global__ __launch_bounds__(256) void k_lnproj(
    const float* __restrict__ x, const float* __restrict__ Wq, const float* __restrict__ bq,
    const float* __restrict__ Wk, const float* __restrict__ bk,
    const float* __restrict__ gamma, const float* __restrict__ beta,
    float* __restrict__ Xn, float* __restrict__ Qb, float* __restrict__ Kb)
{
    __shared__ float xrow[4][64];
    int w = threadIdx.x >> 6, lane = threadIdx.x & 63;
    size_t row = (size_t)blockIdx.x * 4 + w;
    float xv = x[row * 64 + lane];
    float m = xv;
    #pragma unroll
    for (int o = 32; o; o >>= 1) m += __shfl_xor(m, o, 64);
    m *= (1.0f / 64.0f);
    float dv = xv - m;
    float var = dv * dv;
    #pragma unroll
    for (int o = 32; o; o >>= 1) var += __shfl_xor(var, o, 64);
    var *= (1.0f / 64.0f);
    float xg = dv * (1.0f / sqrtf(var + LNEPS)) * gamma[lane] + beta[lane];
    Xn[row * 64 + lane] = xg;
    xrow[w][lane] = xg;
    __syncthreads();
    float q = bq[lane], k = bk[lane];
    #pragma unroll 8
    for (int e = 0; e < 64; e++) {
        float xe = xrow[w][e];
        q += xe * Wq[e * 64 + lane];
        k += xe * Wk[e * 64 + lane];
    }
    Qb[row * 64 + lane] = q;
    Kb[row * 64 + lane] = k;
}

// --------------- radix-select helper: one 8-bit step for one row ---------------
__device__ __forceinline__ void radix_step(const unsigned* histu, int r, int lane,
                                           unsigned& kr, unsigned& pfx, unsigned* prefix_lds)
{
    unsigned c0 = histu[r * 256 + lane * 4 + 0];
    unsigned c1 = histu[r * 256 + lane * 4 + 1];
    unsigned c2 = histu[r * 256 + lane * 4 + 2];
    unsigned c3 = histu[r * 256 + lane * 4 + 3];
    unsigned S = c0 + c1 + c2 + c3;
    unsigned T = S;
    #pragma unroll
    for (int off = 1; off < 64; off <<= 1) {
        unsigned t = __shfl_down(T, off, 64);
        T += (lane + off < 64) ? t : 0u;
    }
    unsigned Tn = T - S;                       // suffix sum starting at lane+1
    unsigned sfx3 = c3 + Tn, sfx2 = c2 + sfx3, sfx1 = c1 + sfx2, sfx0 = c0 + sfx1;
    int hit = -1; unsigned nk = 0u;
    if (sfx3 >= kr && Tn   < kr) { hit = lane * 4 + 3; nk = kr - Tn; }
    if (sfx2 >= kr && sfx3 < kr) { hit = lane * 4 + 2; nk = kr - sfx3; }
    if (sfx1 >= kr && sfx2 < kr) { hit = lane * 4 + 1; nk = kr - sfx2; }
    if (sfx0 >= kr && sfx1 < kr) { hit = lane * 4 + 0; nk = kr - sfx1; }
    unsigned long long mask = __ballot(hit >= 0);
    int src = __ffsll((unsigned long long)mask) - 1;
    int bin = __shfl(hit, src, 64);
    nk = (unsigned)__shfl((int)nk, src, 64);
    pfx = (pfx << 8) | (unsigned)bin;
    kr = nk;
    if (lane == 0) prefix_lds[r] = pfx;
}

// ---------------- Kernel 2: fused scores + top-k threshold + softmax + PV ----------------
__global__ __launch_bounds__(256, 2) void k_attn(
    const float* __restrict__ Xn, const float* __restrict__ Qb, const float* __restrict__ Kb,
    const float* __restrict__ stg, const int* __restrict__ topk_p,
    float* __restrict__ Z)
{
    __shared__ float s_lds[LL * RR];           // [j][r] layout, 59.6 KB
    __shared__ float q_lds[RR][64];
    __shared__ unsigned histu[RR * 256];       // per-row histograms
    __shared__ unsigned prefix_lds[RR];
    __shared__ float thr_lds[RR];
    __shared__ float rcp_lds[RR];
    __shared__ float red[4][RR][64];

    int tid = threadIdx.x;
    int lane = tid & 63, wv = tid >> 6;
    int b = blockIdx.x & 7;
    int chunk = blockIdx.x >> 3;
    int row0 = chunk * RR;
    const float* Kbase = Kb + (size_t)b * LL * 64;
    const float* Xbase = Xn + (size_t)b * LL * 64;

    for (int i = tid; i < RR * 64; i += 256)
        q_lds[i >> 6][i & 63] = Qb[((size_t)b * LL + row0 + (i >> 6)) * 64 + (i & 63)];
    int keff;
    { int tk = *topk_p; keff = (tk < 5) ? tk * NN : tk; }
    __syncthreads();

    // ---- scores: dg = q . k, register-blocked over d-chunks ----
    float dgacc[RR * NJ];
    #pragma unroll
    for (int i = 0; i < RR * NJ; i++) dgacc[i] = 0.f;
    for (int dc = 0; dc < 64; dc += 8) {
        float qc[RR * 8];
        #pragma unroll
        for (int r = 0; r < RR; r++)
            #pragma unroll
            for (int u = 0; u < 8; u++) qc[r * 8 + u] = q_lds[r][dc + u];
        #pragma unroll
        for (int sl = 0; sl < NJ; sl++) {
            int j = tid + sl * 256;
            if (j < LL) {
                const float4* kp = (const float4*)(Kbase + (size_t)j * 64 + dc);
                float4 k0 = kp[0], k1 = kp[1];
                float kv[8] = {k0.x, k0.y, k0.z, k0.w, k1.x, k1.y, k1.z, k1.w};
                #pragma unroll
                for (int r = 0; r < RR; r++) {
                    float a = 0.f;
                    #pragma unroll
                    for (int u = 0; u < 8; u++) a += qc[r * 8 + u] * kv[u];
                    dgacc[r * NJ + sl] += a;
                }
            }
        }
    }
    // ---- s = sigmoid(dg/8) * stg -> LDS ----
    const float* stgp = stg + ((size_t)b * LL + row0) * LL;
    #pragma unroll
    for (int sl = 0; sl < NJ; sl++) {
        int j = tid + sl * 256;
        if (j < LL) {
            #pragma unroll
            for (int r = 0; r < RR; r++) {
                float dg = dgacc[r * NJ + sl] * 0.125f;
                float sg = 1.0f / (1.0f + expf(-dg));
                s_lds[j * RR + r] = sg * stgp[(size_t)r * LL + j];
            }
        }
    }
    __syncthreads();

    // ---- exact k-th largest per row: 4x8-bit radix select on float bits (s >= 0) ----
    unsigned pfxA = 0u, pfxB = 0u, krA = (unsigned)keff, krB = (unsigned)keff;
    for (int pass = 0; pass < 4; pass++) {
        int shift = 24 - pass * 8;
        #pragma unroll
        for (int i = 0; i < RR; i++) histu[i * 256 + tid] = 0u;
        __syncthreads();
        unsigned pf[RR];
        #pragma unroll
        for (int r = 0; r < RR; r++) pf[r] = prefix_lds[r];   // unused on pass 0
        for (int j = tid; j < LL; j += 256) {
            #pragma unroll
            for (int r = 0; r < RR; r++) {
                unsigned vb = __float_as_uint(s_lds[j * RR + r]);
                bool match = (pass == 0) || ((vb >> (shift + 8)) == pf[r]);
                if (match) atomicAdd(&histu[r * 256 + ((vb >> shift) & 255u)], 1u);
            }
        }
        __syncthreads();
        radix_step(histu, wv, lane, krA, pfxA, prefix_lds);       // rows 0..3
        if (wv < 2) radix_step(histu, wv + 4, lane, krB, pfxB, prefix_lds); // rows 4,5
        __syncthreads();
    }
    if (lane == 0) {
        thr_lds[wv] = __uint_as_float(pfxA);
        if (wv < 2) thr_lds[wv + 4] = __uint_as_float(pfxB);
    }
    __syncthreads();

    // ---- row max ----
    float thrv[RR], mxv[RR];
    #pragma unroll
    for (int r = 0; r < RR; r++) { thrv[r] = thr_lds[r]; mxv[r] = 0.f; }
    for (int j = tid; j < LL; j += 256) {
        #pragma unroll
        for (int r = 0; r < RR; r++) mxv[r] = fmaxf(mxv[r], s_lds[j * RR + r]);
    }
    #pragma unroll
    for (int r = 0; r < RR; r++) {
        #pragma unroll
        for (int o = 32; o; o >>= 1) mxv[r] = fmaxf(mxv[r], __shfl_xor(mxv[r], o, 64));
    }
    if (lane == 0) {
        #pragma unroll
        for (int r = 0; r < RR; r++) red[wv][r][0] = mxv[r];
    }
    __syncthreads();
    #pragma unroll
    for (int r = 0; r < RR; r++)
        mxv[r] = fmaxf(fmaxf(red[0][r][0], red[1][r][0]), fmaxf(red[2][r][0], red[3][r][0]));
    __syncthreads();

    // ---- e = (s > thr) ? exp(s - max) : 0, in place; accumulate sums ----
    float sme[RR];
    #pragma unroll
    for (int r = 0; r < RR; r++) sme[r] = 0.f;
    for (int j = tid; j < LL; j += 256) {
        #pragma unroll
        for (int r = 0; r < RR; r++) {
            float sv = s_lds[j * RR + r];
            float e = (sv > thrv[r]) ? expf(sv - mxv[r]) : 0.f;
            s_lds[j * RR + r] = e;
            sme[r] += e;
        }
    }
    #pragma unroll
    for (int r = 0; r < RR; r++) {
        #pragma unroll
        for (int o = 32; o; o >>= 1) sme[r] += __shfl_xor(sme[r], o, 64);
    }
    if (lane == 0) {
        #pragma unroll
        for (int r = 0; r < RR; r++) red[wv][r][1] = sme[r];
    }
    __syncthreads();
    if (tid < RR) {
        float tot = red[0][tid][1] + red[1][tid][1] + red[2][tid][1] + red[3][tid][1];
        rcp_lds[tid] = 1.0f / tot;
    }
    __syncthreads();

    // ---- o = e @ Xn (wave-contiguous j chunks), then z = o/sum + x_ ----
    float acc[RR];
    #pragma unroll
    for (int r = 0; r < RR; r++) acc[r] = 0.f;
    {
        const float* xp = Xbase + (size_t)(wv * 621) * 64 + lane;
        int base = (wv * 621) * RR;
        for (int jj = 0; jj < 621; jj++) {
            float xv2 = xp[(size_t)jj * 64];
            #pragma unroll
            for (int r = 0; r < RR; r++) acc[r] += s_lds[base + jj * RR + r] * xv2;
        }
        #pragma unroll
        for (int r = 0; r < RR; r++) red[wv][r][lane] = acc[r];
    }
    __syncthreads();
    for (int i = tid; i < RR * 64; i += 256) {
        int r = i >> 6, d = i & 63;
        float o = (red[0][r][d] + red[1][r][d]) + (red[2][r][d] + red[3][r][d]);
        o *= rcp_lds[r];
        size_t grow = (size_t)b * LL + row0 + r;
        Z[grow * 64 + d] = o + Xbase[(size_t)(row0 + r) * 64 + d];
    }
}

// ---------------- Kernel 3: fused LN + FFN + residual ----------------
__global__ __launch_bounds__(256) void k_ffn(
    const float* __restrict__ Zb, const float* __restrict__ fg, const float* __restrict__ fb,
    const float* __restrict__ w1, const float* __restrict__ b1,
    const float* __restrict__ w2, const float* __restrict__ b2,
    float* __restrict__ out)
{
    const int G = 16;
    __shared__ float zr[G][64];
    __shared__ float zl[G][64];
    __shared__ float h[G][DHID];
    int tid = threadIdx.x;
    int w = tid >> 6, lane = tid & 63;
    size_t row0 = (size_t)blockIdx.x * G;
    for (int rr = w; rr < G; rr += 4) {
        float zv = Zb[(row0 + rr) * 64 + lane];
        zr[rr][lane] = zv;
        float m = zv;
        #pragma unroll
        for (int o = 32; o; o >>= 1) m += __shfl_xor(m, o, 64);
        m *= (1.0f / 64.0f);
        float dv = zv - m;
        float var = dv * dv;
        #pragma unroll
        for (int o = 32; o; o >>= 1) var += __shfl_xor(var, o, 64);
        var *= (1.0f / 64.0f);
        zl[rr][lane] = dv * (1.0f / sqrtf(var + LNEPS)) * fg[lane] + fb[lane];
    }
    __syncthreads();
    float hacc[G];
    #pragma unroll
    for (int g = 0; g < G; g++) hacc[g] = 0.f;
    for (int d = 0; d < 64; d++) {
        float wv1 = w1[d * DHID + tid];
        #pragma unroll
        for (int g = 0; g < G; g++) hacc[g] += zl[g][d] * wv1;
    }
    float b1v = b1[tid];
    #pragma unroll
    for (int g = 0; g < G; g++) h[g][tid] = fmaxf(hacc[g] + b1v, 0.f);
    __syncthreads();
    float oacc[4] = {0.f, 0.f, 0.f, 0.f};
    for (int i = 0; i < DHID; i++) {
        float wv2 = w2[i * 64 + lane];
        #pragma unroll
        for (int rr = 0; rr < 4; rr++) oacc[rr] += h[w * 4 + rr][i] * wv2;
    }
    float b2v = b2[lane];
    #pragma unroll
    for (int rr = 0; rr < 4; rr++)
        out[(row0 + w * 4 + rr) * 64 + lane] = zr[w * 4 + rr][lane] + oacc[rr] + b2v;
}

extern "C" void kernel_launch(void* const* d_in, const int* in_sizes, int n_in,
                              void* d_out, int out_size, void* d_ws, size_t ws_size,
                              hipStream_t stream)
{
    const float* x      = (const float*)d_in[0];
    const float* stg    = (const float*)d_in[1];
    const float* Wq     = (const float*)d_in[2];
    const float* bq     = (const float*)d_in[3];
    const float* Wk     = (const float*)d_in[4];
    const float* bk     = (const float*)d_in[5];
    const float* gamma  = (const float*)d_in[6];
    const float* beta   = (const float*)d_in[7];
    const float* fgamma = (const float*)d_in[8];
    const float* fbeta  = (const float*)d_in[9];
    const float* w1     = (const float*)d_in[10];
    const float* b1     = (const float*)d_in[11];
    const float* w2     = (const float*)d_in[12];
    const float* b2     = (const float*)d_in[13];
    const int*   topk   = (const int*)d_in[14];
    float* out = (float*)d_out;

    const size_t rows = (size_t)NBATCH * NTOK * NN;   // 19872
    float* Xn = (float*)d_ws;
    float* Qb = Xn + rows * 64;
    float* Kb = Qb + rows * 64;
    float* Z  = Kb + rows * 64;

    k_lnproj<<<(int)(rows / 4), 256, 0, stream>>>(x, Wq, bq, Wk, bk, gamma, beta, Xn, Qb, Kb);
    k_attn<<<NBATCH * (LL / RR), 256, 0, stream>>>(Xn, Qb, Kb, stg, topk, Z);
    k_ffn<<<(int)(rows / 16), 256, 0, stream>>>(Z, fgamma, fbeta, w1, b1, w2, b2, out);
}